// Round 16
// baseline (144.992 us; speedup 1.0000x reference)
//
#include <hip/hip_runtime.h>

// IGD metric kernel for MI355X (gfx950) — R16: 128 rows/wave (4 MFMAs per B-fragment load).
// d2(i,j) = pfsq[i] + xsq[j] + dot(e4m3(-2*pf_i), e4m3(x_j)); norms in fp32 from HW-DECODED fp8.
// R15 accounting: igd runs at ~656 cyc per wave-unit-step vs ~232 issue demand; residual ~420
// cyc/step survived delivery/ILP/VALU/TLP/barrier changes. Last untested axis: intensity per
// B-load. R16 halves step count at constant MFMA+VALU totals: each wave handles 4 row-groups
// (128 rows), MTILE=512, NSPLIT=16 -> grid (32,16)=512 = exactly 2 blocks/CU (2 waves/SIMD),
// ucount=32 exactly. launch_bounds(256,2) -> VGPR cap 256 for the ~195-reg working set (NOT
// repeating R2/R12's forced-cap spill). Pack (HW cvt) and staging (async DMA dbuf) == R15.
// Harness poison fill of ws (~42 us @6.5TB/s) is a fixed floor inside the timed window.

typedef float f32x16 __attribute__((ext_vector_type(16)));
typedef float f32x2 __attribute__((ext_vector_type(2)));
typedef int i32x8 __attribute__((ext_vector_type(8)));
typedef unsigned long long u64;

#define DIM 64
#define NSPLIT 16
#define UNITB 2048            // bytes per 32-col unit: 4 qfrags x 64 lanes x 8 B
#define CHUNKU 8              // units per LDS chunk
#define CHUNKB (CHUNKU * UNITB)   // 16 KB
#define MTILE 512             // rows per block (4 waves x 128 rows)
#define GROUPS 4              // 32-row groups per wave

union BFrag { u64 q[4]; i32x8 v; };

// async global->LDS DMA, 16 B/lane (global_load_lds_dwordx4) and 4 B/lane
__device__ __forceinline__ void g2lds16(const void* g, void* l) {
    __builtin_amdgcn_global_load_lds(
        (const __attribute__((address_space(1))) unsigned int*)g,
        (__attribute__((address_space(3))) unsigned int*)l, 16, 0, 0);
}
__device__ __forceinline__ void g2lds4(const void* g, void* l) {
    __builtin_amdgcn_global_load_lds(
        (const __attribute__((address_space(1))) unsigned int*)g,
        (__attribute__((address_space(3))) unsigned int*)l, 4, 0, 0);
}

// ---------------- pack (HW fp8 converters) ----------------
__device__ __forceinline__ void encode16(const float* f, u64 w[2], float& sumsq) {
    unsigned int w32[4];
#pragma unroll
    for (int k = 0; k < 4; ++k) {
        int lo = __builtin_amdgcn_cvt_pk_fp8_f32(f[4 * k],     f[4 * k + 1], 0,  false);
        w32[k] = __builtin_amdgcn_cvt_pk_fp8_f32(f[4 * k + 2], f[4 * k + 3], lo, true);
    }
#pragma unroll
    for (int k = 0; k < 4; ++k) {
        f32x2 d0 = __builtin_amdgcn_cvt_pk_f32_fp8(w32[k], false);
        f32x2 d1 = __builtin_amdgcn_cvt_pk_f32_fp8(w32[k], true);
        sumsq += d0.x * d0.x + d0.y * d0.y + d1.x * d1.x + d1.y * d1.y;
    }
    w[0] = (u64)w32[0] | ((u64)w32[1] << 32);
    w[1] = (u64)w32[2] | ((u64)w32[3] << 32);
}

// Bp layout (32x32x64 B-operand): lane L = h*32 + c31 holds col = u*32+c31, k = h*32 + 0..31:
//   Bp[u*2048 + q*512 + L*8 + b] = e4m3(x[col][h*32 + q*8 + b]).
// xsq[col] = exact fp32 sum of squares of decoded values.
// pf -> Ab row-major fp8(-2*pf); pfsq = 0.25*sum(dec^2).
__global__ void pack_kernel(const float* __restrict__ x, const float* __restrict__ pf,
                            unsigned char* __restrict__ Bp, unsigned char* __restrict__ Ab,
                            float* __restrict__ xsq, float* __restrict__ pfsq,
                            float* __restrict__ out, int N, int M) {
    int gid = blockIdx.x * blockDim.x + threadIdx.x;
    if (gid == 0) out[0] = 0.f;
    if (gid < N * 4) {
        int col = gid >> 2, t = gid & 3;
        const float* s = x + (size_t)col * DIM + t * 16;
        float4 v0 = *(const float4*)(s);
        float4 v1 = *(const float4*)(s + 4);
        float4 v2 = *(const float4*)(s + 8);
        float4 v3 = *(const float4*)(s + 12);
        float f[16] = {v0.x, v0.y, v0.z, v0.w, v1.x, v1.y, v1.z, v1.w,
                       v2.x, v2.y, v2.z, v2.w, v3.x, v3.y, v3.z, v3.w};
        float partial = 0.f;
        u64 w[2];
        encode16(f, w, partial);
        int u = col >> 5, c31 = col & 31;
        unsigned char* ub = Bp + (size_t)u * UNITB;
        int h = t >> 1;
#pragma unroll
        for (int ss = 0; ss < 2; ++ss) {
            int q = (t & 1) * 2 + ss;
            *(u64*)(ub + (size_t)q * 512 + (size_t)(h * 32 + c31) * 8) = w[ss];
        }
        partial += __shfl_xor(partial, 1);
        partial += __shfl_xor(partial, 2);
        if (t == 0) xsq[col] = partial;
    } else {
        int g = gid - N * 4;
        int row = g >> 2, q = g & 3;
        if (row >= M) return;
        const float* s = pf + (size_t)row * DIM + q * 16;
        float4 v0 = *(const float4*)(s);
        float4 v1 = *(const float4*)(s + 4);
        float4 v2 = *(const float4*)(s + 8);
        float4 v3 = *(const float4*)(s + 12);
        float f[16] = {v0.x, v0.y, v0.z, v0.w, v1.x, v1.y, v1.z, v1.w,
                       v2.x, v2.y, v2.z, v2.w, v3.x, v3.y, v3.z, v3.w};
#pragma unroll
        for (int j = 0; j < 16; ++j) f[j] *= -2.f;
        float partial = 0.f;
        u64 w[2];
        encode16(f, w, partial);
        *(u64*)(Ab + (size_t)row * DIM + q * 16)     = w[0];
        *(u64*)(Ab + (size_t)row * DIM + q * 16 + 8) = w[1];
        partial += __shfl_xor(partial, 1);
        partial += __shfl_xor(partial, 2);
        if (q == 0) pfsq[row] = partial * 0.25f;
    }
}

// ---------------- main: 4 waves x 128 rows, async-LDS dbuf, 4 MFMA per B-load ----------------
__global__ __launch_bounds__(256, 2)
void igd_main(const unsigned char* __restrict__ A, const unsigned char* __restrict__ Bp,
              const float* __restrict__ xsq, float* __restrict__ partial, int N) {
    __shared__ unsigned char ldsB[2][CHUNKB];     // 32 KB
    __shared__ float ldsX[2][CHUNKU * 32];        // 2 KB
    const int tid = threadIdx.x;
    const int mTile  = blockIdx.x;
    const int nsplit = blockIdx.y;
    const int lane = tid & 63;
    const int wave = tid >> 6;
    const int half = lane >> 5;
    const int l31  = lane & 31;
    const int rowBase = mTile * MTILE + wave * (32 * GROUPS);

    const int utotal = N / 32;                    // 512
    const int ucount = utotal / NSPLIT;           // 32 exactly
    const int ustart = nsplit * ucount;
    const int nch = ucount / CHUNKU;              // 4

    // Persistent A operands: 4 row-groups; lane holds A[row=l31+32g][k=half*32..+31] (32 B)
    BFrag a[GROUPS];
#pragma unroll
    for (int g = 0; g < GROUPS; ++g) {
        const unsigned char* ap = A + (size_t)(rowBase + 32 * g + l31) * DIM + half * 32;
#pragma unroll
        for (int qq = 0; qq < 4; ++qq)
            a[g].q[qq] = *(const u64*)(ap + qq * 8);
    }

    const unsigned char* gB = Bp + (size_t)ustart * UNITB;
    const float* gX = xsq + ustart * 32;

#define STAGE(c, buf)                                                          \
    {                                                                          \
        const unsigned char* src = gB + (size_t)(c) * CHUNKB;                  \
        _Pragma("unroll")                                                      \
        for (int i = 0; i < 4; ++i) {                                          \
            int off = i * 4096 + tid * 16;                                     \
            g2lds16(src + off, &ldsB[buf][off]);                               \
        }                                                                      \
        if (tid < CHUNKU * 32)                                                 \
            g2lds4(gX + (c) * (CHUNKU * 32) + tid, &ldsX[buf][tid]);           \
    }

    f32x16 zero, m[GROUPS];
#pragma unroll
    for (int r = 0; r < 16; ++r) {
        zero[r] = 0.f;
#pragma unroll
        for (int g = 0; g < GROUPS; ++g) m[g][r] = 1e30f;
    }

#define LOADF(rr, lb, u)                                                       \
    {                                                                          \
        const unsigned char* p = (lb) + (u) * UNITB;                           \
        rr.q[0] = *(const u64*)(p);                                            \
        rr.q[1] = *(const u64*)(p + 512);                                      \
        rr.q[2] = *(const u64*)(p + 1024);                                     \
        rr.q[3] = *(const u64*)(p + 1536);                                     \
    }

    // Unity E8M0 scales (0x7F = 2^0): bit-identical to non-scaled fp8 accumulation.
    // 4 independent MFMAs per B-fragment; mins applied per group after issue of all 4.
#define STEP4(bfrag, xq)                                                       \
    {                                                                          \
        f32x16 acc[GROUPS];                                                    \
        _Pragma("unroll")                                                      \
        for (int g = 0; g < GROUPS; ++g)                                       \
            acc[g] = __builtin_amdgcn_mfma_scale_f32_32x32x64_f8f6f4(          \
                a[g].v, bfrag.v, zero, 0, 0, 0, 0x7F7F7F7F, 0, 0x7F7F7F7F);    \
        _Pragma("unroll")                                                      \
        for (int g = 0; g < GROUPS; ++g) {                                     \
            _Pragma("unroll")                                                  \
            for (int r = 0; r < 16; ++r)                                       \
                m[g][r] = fminf(m[g][r], acc[g][r] + (xq));                    \
        }                                                                      \
    }

    STAGE(0, 0);
    __syncthreads();   // drains the async loads (vmcnt) + barrier

    for (int c = 0; c < nch; ++c) {
        const int buf = c & 1;
        if (c + 1 < nch) STAGE(c + 1, buf ^ 1);   // async; drains only at the next barrier
        const unsigned char* lb = &ldsB[buf][0] + lane * 8;
        const float* lx = &ldsX[buf][0] + l31;
        BFrag b0, b1;
        LOADF(b0, lb, 0);
#pragma unroll
        for (int u = 0; u < CHUNKU; u += 2) {
            LOADF(b1, lb, u + 1);
            STEP4(b0, lx[u * 32]);
            if (u + 2 < CHUNKU) LOADF(b0, lb, u + 2);
            STEP4(b1, lx[(u + 1) * 32]);
        }
        __syncthreads();
    }
#undef STAGE
#undef LOADF
#undef STEP4

    // cross-lane min over the 32 lanes sharing a row
#pragma unroll
    for (int mask = 1; mask <= 16; mask <<= 1) {
#pragma unroll
        for (int g = 0; g < GROUPS; ++g)
#pragma unroll
            for (int r = 0; r < 16; ++r)
                m[g][r] = fminf(m[g][r], __shfl_xor(m[g][r], mask));
    }
    if (l31 == 0) {
        // C/D layout (shape-determined, FMT-independent): row = (r&3)+8*(r>>2)+4*half
#pragma unroll
        for (int g = 0; g < GROUPS; ++g)
#pragma unroll
            for (int r = 0; r < 16; ++r) {
                int row0 = rowBase + 32 * g + (r & 3) + 8 * (r >> 2) + 4 * half;
                partial[(size_t)row0 * NSPLIT + nsplit] = m[g][r];
            }
    }
}

// ---------------- reduce: min over splits, add pfsq, sqrt, mean ----------------
__global__ void reduce_kernel(const float* __restrict__ partial, const float* __restrict__ pfsq,
                              float* __restrict__ out, int M, float invM) {
    int row = blockIdx.x * blockDim.x + threadIdx.x;
    float v = 0.f;
    if (row < M) {
        const float* p = partial + (size_t)row * NSPLIT;
        float mn = 3.4e38f;
#pragma unroll
        for (int s = 0; s < NSPLIT; ++s) mn = fminf(mn, p[s]);
        float d2 = mn + pfsq[row];
        v = sqrtf(fmaxf(d2, 0.f)) * invM;
    }
#pragma unroll
    for (int m = 1; m < 64; m <<= 1) v += __shfl_xor(v, m);
    __shared__ float wsum[4];
    int lane = threadIdx.x & 63, w = threadIdx.x >> 6;
    if (lane == 0) wsum[w] = v;
    __syncthreads();
    if (threadIdx.x == 0) atomicAdd(out, wsum[0] + wsum[1] + wsum[2] + wsum[3]);
}

extern "C" void kernel_launch(void* const* d_in, const int* in_sizes, int n_in,
                              void* d_out, int out_size, void* d_ws, size_t ws_size,
                              hipStream_t stream) {
    const float* x  = (const float*)d_in[0];   // [N, 64]
    const float* pf = (const float*)d_in[1];   // [M, 64]
    const int N = in_sizes[0] / DIM;
    const int M = in_sizes[1] / DIM;

    char* ws = (char*)d_ws;
    unsigned char* Bp = (unsigned char*)ws;                        // N*64 bytes (packed fp8)
    unsigned char* Ab = (unsigned char*)(ws + (size_t)N * DIM);    // M*64 bytes
    float* xsq  = (float*)(ws + (size_t)(N + M) * DIM);            // N floats
    float* pfsq = xsq + N;                                         // M floats
    float* part = pfsq + M;                                        // M*NSPLIT floats

    int packThreads = (N + M) * 4;
    pack_kernel<<<dim3((packThreads + 255) / 256), 256, 0, stream>>>(
        x, pf, Bp, Ab, xsq, pfsq, (float*)d_out, N, M);
    igd_main<<<dim3(M / MTILE, NSPLIT), 256, 0, stream>>>(Ab, Bp, xsq, part, N);
    reduce_kernel<<<dim3((M + 255) / 256), 256, 0, stream>>>(part, pfsq, (float*)d_out, M, 1.f / (float)M);
}

// Round 17
// 141.632 us; speedup vs baseline: 1.0237x; 1.0237x over previous
//
#include <hip/hip_runtime.h>

// IGD metric kernel for MI355X (gfx950) — R17: R16 intensity test with PINNED occupancy.
// d2(i,j) = pfsq[i] + xsq[j] + dot(e4m3(-2*pf_i), e4m3(x_j)); norms in fp32 from HW-DECODED fp8.
// R16 post-mortem: __launch_bounds__(256,2) is only a MINIMUM waves/EU — the backend targeted 4
// waves/SIMD, capped VGPR at 128, and spilled the ~195-reg set (WRITE 99MB). Third confounded
// register experiment. R17: __attribute__((amdgpu_waves_per_eu(2,2))) bounds occupancy from BOTH
// sides -> 256-VGPR budget, no spill incentive. Otherwise byte-identical to R16: 4 row-groups
// per wave (128 rows), 4 MFMAs per B-fragment load (halved step count at constant pipe work),
// MTILE=512, NSPLIT=16, grid (32,16)=512 = 2 blocks/CU, async-DMA LDS double-buffer.
// Harness poison fill of ws (~42 us @6.5TB/s) is a fixed floor inside the timed window.

typedef float f32x16 __attribute__((ext_vector_type(16)));
typedef float f32x2 __attribute__((ext_vector_type(2)));
typedef int i32x8 __attribute__((ext_vector_type(8)));
typedef unsigned long long u64;

#define DIM 64
#define NSPLIT 16
#define UNITB 2048            // bytes per 32-col unit: 4 qfrags x 64 lanes x 8 B
#define CHUNKU 8              // units per LDS chunk
#define CHUNKB (CHUNKU * UNITB)   // 16 KB
#define MTILE 512             // rows per block (4 waves x 128 rows)
#define GROUPS 4              // 32-row groups per wave

union BFrag { u64 q[4]; i32x8 v; };

// async global->LDS DMA, 16 B/lane (global_load_lds_dwordx4) and 4 B/lane
__device__ __forceinline__ void g2lds16(const void* g, void* l) {
    __builtin_amdgcn_global_load_lds(
        (const __attribute__((address_space(1))) unsigned int*)g,
        (__attribute__((address_space(3))) unsigned int*)l, 16, 0, 0);
}
__device__ __forceinline__ void g2lds4(const void* g, void* l) {
    __builtin_amdgcn_global_load_lds(
        (const __attribute__((address_space(1))) unsigned int*)g,
        (__attribute__((address_space(3))) unsigned int*)l, 4, 0, 0);
}

// ---------------- pack (HW fp8 converters) ----------------
__device__ __forceinline__ void encode16(const float* f, u64 w[2], float& sumsq) {
    unsigned int w32[4];
#pragma unroll
    for (int k = 0; k < 4; ++k) {
        int lo = __builtin_amdgcn_cvt_pk_fp8_f32(f[4 * k],     f[4 * k + 1], 0,  false);
        w32[k] = __builtin_amdgcn_cvt_pk_fp8_f32(f[4 * k + 2], f[4 * k + 3], lo, true);
    }
#pragma unroll
    for (int k = 0; k < 4; ++k) {
        f32x2 d0 = __builtin_amdgcn_cvt_pk_f32_fp8(w32[k], false);
        f32x2 d1 = __builtin_amdgcn_cvt_pk_f32_fp8(w32[k], true);
        sumsq += d0.x * d0.x + d0.y * d0.y + d1.x * d1.x + d1.y * d1.y;
    }
    w[0] = (u64)w32[0] | ((u64)w32[1] << 32);
    w[1] = (u64)w32[2] | ((u64)w32[3] << 32);
}

// Bp layout (32x32x64 B-operand): lane L = h*32 + c31 holds col = u*32+c31, k = h*32 + 0..31:
//   Bp[u*2048 + q*512 + L*8 + b] = e4m3(x[col][h*32 + q*8 + b]).
// xsq[col] = exact fp32 sum of squares of decoded values.
// pf -> Ab row-major fp8(-2*pf); pfsq = 0.25*sum(dec^2).
__global__ void pack_kernel(const float* __restrict__ x, const float* __restrict__ pf,
                            unsigned char* __restrict__ Bp, unsigned char* __restrict__ Ab,
                            float* __restrict__ xsq, float* __restrict__ pfsq,
                            float* __restrict__ out, int N, int M) {
    int gid = blockIdx.x * blockDim.x + threadIdx.x;
    if (gid == 0) out[0] = 0.f;
    if (gid < N * 4) {
        int col = gid >> 2, t = gid & 3;
        const float* s = x + (size_t)col * DIM + t * 16;
        float4 v0 = *(const float4*)(s);
        float4 v1 = *(const float4*)(s + 4);
        float4 v2 = *(const float4*)(s + 8);
        float4 v3 = *(const float4*)(s + 12);
        float f[16] = {v0.x, v0.y, v0.z, v0.w, v1.x, v1.y, v1.z, v1.w,
                       v2.x, v2.y, v2.z, v2.w, v3.x, v3.y, v3.z, v3.w};
        float partial = 0.f;
        u64 w[2];
        encode16(f, w, partial);
        int u = col >> 5, c31 = col & 31;
        unsigned char* ub = Bp + (size_t)u * UNITB;
        int h = t >> 1;
#pragma unroll
        for (int ss = 0; ss < 2; ++ss) {
            int q = (t & 1) * 2 + ss;
            *(u64*)(ub + (size_t)q * 512 + (size_t)(h * 32 + c31) * 8) = w[ss];
        }
        partial += __shfl_xor(partial, 1);
        partial += __shfl_xor(partial, 2);
        if (t == 0) xsq[col] = partial;
    } else {
        int g = gid - N * 4;
        int row = g >> 2, q = g & 3;
        if (row >= M) return;
        const float* s = pf + (size_t)row * DIM + q * 16;
        float4 v0 = *(const float4*)(s);
        float4 v1 = *(const float4*)(s + 4);
        float4 v2 = *(const float4*)(s + 8);
        float4 v3 = *(const float4*)(s + 12);
        float f[16] = {v0.x, v0.y, v0.z, v0.w, v1.x, v1.y, v1.z, v1.w,
                       v2.x, v2.y, v2.z, v2.w, v3.x, v3.y, v3.z, v3.w};
#pragma unroll
        for (int j = 0; j < 16; ++j) f[j] *= -2.f;
        float partial = 0.f;
        u64 w[2];
        encode16(f, w, partial);
        *(u64*)(Ab + (size_t)row * DIM + q * 16)     = w[0];
        *(u64*)(Ab + (size_t)row * DIM + q * 16 + 8) = w[1];
        partial += __shfl_xor(partial, 1);
        partial += __shfl_xor(partial, 2);
        if (q == 0) pfsq[row] = partial * 0.25f;
    }
}

// ---------------- main: 4 waves x 128 rows, pinned 2 waves/EU, 4 MFMA per B-load -------------
__global__ __attribute__((amdgpu_flat_work_group_size(256, 256), amdgpu_waves_per_eu(2, 2)))
void igd_main(const unsigned char* __restrict__ A, const unsigned char* __restrict__ Bp,
              const float* __restrict__ xsq, float* __restrict__ partial, int N) {
    __shared__ unsigned char ldsB[2][CHUNKB];     // 32 KB
    __shared__ float ldsX[2][CHUNKU * 32];        // 2 KB
    const int tid = threadIdx.x;
    const int mTile  = blockIdx.x;
    const int nsplit = blockIdx.y;
    const int lane = tid & 63;
    const int wave = tid >> 6;
    const int half = lane >> 5;
    const int l31  = lane & 31;
    const int rowBase = mTile * MTILE + wave * (32 * GROUPS);

    const int utotal = N / 32;                    // 512
    const int ucount = utotal / NSPLIT;           // 32 exactly
    const int ustart = nsplit * ucount;
    const int nch = ucount / CHUNKU;              // 4

    // Persistent A operands: 4 row-groups; lane holds A[row=l31+32g][k=half*32..+31] (32 B)
    BFrag a[GROUPS];
#pragma unroll
    for (int g = 0; g < GROUPS; ++g) {
        const unsigned char* ap = A + (size_t)(rowBase + 32 * g + l31) * DIM + half * 32;
#pragma unroll
        for (int qq = 0; qq < 4; ++qq)
            a[g].q[qq] = *(const u64*)(ap + qq * 8);
    }

    const unsigned char* gB = Bp + (size_t)ustart * UNITB;
    const float* gX = xsq + ustart * 32;

#define STAGE(c, buf)                                                          \
    {                                                                          \
        const unsigned char* src = gB + (size_t)(c) * CHUNKB;                  \
        _Pragma("unroll")                                                      \
        for (int i = 0; i < 4; ++i) {                                          \
            int off = i * 4096 + tid * 16;                                     \
            g2lds16(src + off, &ldsB[buf][off]);                               \
        }                                                                      \
        if (tid < CHUNKU * 32)                                                 \
            g2lds4(gX + (c) * (CHUNKU * 32) + tid, &ldsX[buf][tid]);           \
    }

    f32x16 zero, m[GROUPS];
#pragma unroll
    for (int r = 0; r < 16; ++r) {
        zero[r] = 0.f;
#pragma unroll
        for (int g = 0; g < GROUPS; ++g) m[g][r] = 1e30f;
    }

#define LOADF(rr, lb, u)                                                       \
    {                                                                          \
        const unsigned char* p = (lb) + (u) * UNITB;                           \
        rr.q[0] = *(const u64*)(p);                                            \
        rr.q[1] = *(const u64*)(p + 512);                                      \
        rr.q[2] = *(const u64*)(p + 1024);                                     \
        rr.q[3] = *(const u64*)(p + 1536);                                     \
    }

    // Unity E8M0 scales (0x7F = 2^0): bit-identical to non-scaled fp8 accumulation.
#define STEP4(bfrag, xq)                                                       \
    {                                                                          \
        f32x16 acc[GROUPS];                                                    \
        _Pragma("unroll")                                                      \
        for (int g = 0; g < GROUPS; ++g)                                       \
            acc[g] = __builtin_amdgcn_mfma_scale_f32_32x32x64_f8f6f4(          \
                a[g].v, bfrag.v, zero, 0, 0, 0, 0x7F7F7F7F, 0, 0x7F7F7F7F);    \
        _Pragma("unroll")                                                      \
        for (int g = 0; g < GROUPS; ++g) {                                     \
            _Pragma("unroll")                                                  \
            for (int r = 0; r < 16; ++r)                                       \
                m[g][r] = fminf(m[g][r], acc[g][r] + (xq));                    \
        }                                                                      \
    }

    STAGE(0, 0);
    __syncthreads();   // drains the async loads (vmcnt) + barrier

    for (int c = 0; c < nch; ++c) {
        const int buf = c & 1;
        if (c + 1 < nch) STAGE(c + 1, buf ^ 1);   // async; drains only at the next barrier
        const unsigned char* lb = &ldsB[buf][0] + lane * 8;
        const float* lx = &ldsX[buf][0] + l31;
        BFrag b0, b1;
        LOADF(b0, lb, 0);
#pragma unroll
        for (int u = 0; u < CHUNKU; u += 2) {
            LOADF(b1, lb, u + 1);
            STEP4(b0, lx[u * 32]);
            if (u + 2 < CHUNKU) LOADF(b0, lb, u + 2);
            STEP4(b1, lx[(u + 1) * 32]);
        }
        __syncthreads();
    }
#undef STAGE
#undef LOADF
#undef STEP4

    // cross-lane min over the 32 lanes sharing a row
#pragma unroll
    for (int mask = 1; mask <= 16; mask <<= 1) {
#pragma unroll
        for (int g = 0; g < GROUPS; ++g)
#pragma unroll
            for (int r = 0; r < 16; ++r)
                m[g][r] = fminf(m[g][r], __shfl_xor(m[g][r], mask));
    }
    if (l31 == 0) {
        // C/D layout (shape-determined, FMT-independent): row = (r&3)+8*(r>>2)+4*half
#pragma unroll
        for (int g = 0; g < GROUPS; ++g)
#pragma unroll
            for (int r = 0; r < 16; ++r) {
                int row0 = rowBase + 32 * g + (r & 3) + 8 * (r >> 2) + 4 * half;
                partial[(size_t)row0 * NSPLIT + nsplit] = m[g][r];
            }
    }
}

// ---------------- reduce: min over splits, add pfsq, sqrt, mean ----------------
__global__ void reduce_kernel(const float* __restrict__ partial, const float* __restrict__ pfsq,
                              float* __restrict__ out, int M, float invM) {
    int row = blockIdx.x * blockDim.x + threadIdx.x;
    float v = 0.f;
    if (row < M) {
        const float* p = partial + (size_t)row * NSPLIT;
        float mn = 3.4e38f;
#pragma unroll
        for (int s = 0; s < NSPLIT; ++s) mn = fminf(mn, p[s]);
        float d2 = mn + pfsq[row];
        v = sqrtf(fmaxf(d2, 0.f)) * invM;
    }
#pragma unroll
    for (int m = 1; m < 64; m <<= 1) v += __shfl_xor(v, m);
    __shared__ float wsum[4];
    int lane = threadIdx.x & 63, w = threadIdx.x >> 6;
    if (lane == 0) wsum[w] = v;
    __syncthreads();
    if (threadIdx.x == 0) atomicAdd(out, wsum[0] + wsum[1] + wsum[2] + wsum[3]);
}

extern "C" void kernel_launch(void* const* d_in, const int* in_sizes, int n_in,
                              void* d_out, int out_size, void* d_ws, size_t ws_size,
                              hipStream_t stream) {
    const float* x  = (const float*)d_in[0];   // [N, 64]
    const float* pf = (const float*)d_in[1];   // [M, 64]
    const int N = in_sizes[0] / DIM;
    const int M = in_sizes[1] / DIM;

    char* ws = (char*)d_ws;
    unsigned char* Bp = (unsigned char*)ws;                        // N*64 bytes (packed fp8)
    unsigned char* Ab = (unsigned char*)(ws + (size_t)N * DIM);    // M*64 bytes
    float* xsq  = (float*)(ws + (size_t)(N + M) * DIM);            // N floats
    float* pfsq = xsq + N;                                         // M floats
    float* part = pfsq + M;                                        // M*NSPLIT floats

    int packThreads = (N + M) * 4;
    pack_kernel<<<dim3((packThreads + 255) / 256), 256, 0, stream>>>(
        x, pf, Bp, Ab, xsq, pfsq, (float*)d_out, N, M);
    igd_main<<<dim3(M / MTILE, NSPLIT), 256, 0, stream>>>(Ab, Bp, xsq, part, N);
    reduce_kernel<<<dim3((M + 255) / 256), 256, 0, stream>>>(part, pfsq, (float*)d_out, M, 1.f / (float)M);
}